// Round 8
// baseline (36.666 us; speedup 1.0000x reference)
//
#include <hip/hip_runtime.h>
#include <float.h>

#define BB 32
#define CC 128
#define HH 64
#define WW 64

// Block = 256 thr = 4 waves = 4 channels; block covers landmark pair (2p, 2p+1)
// of one (b, channel-group). Pair shares output rows -> full-line stores.
// Grid = 32 b (fastest) * 4 pairs * 32 cg = 4096 blocks.
__global__ __launch_bounds__(256) void roipool_kernel(
    const float* __restrict__ x,   // [B,C,64,64]
    const float* __restrict__ lm,  // [B,16]
    float* __restrict__ out)       // [B,C,32,16]
{
    int blk = blockIdx.x;
    int b   = blk & 31;
    int p   = (blk >> 5) & 3;     // landmark pair
    int cg  = blk >> 7;           // 0..31

    int wave = threadIdx.x >> 6;
    int lane = threadIdx.x & 63;
    int c = cg * 4 + wave;

    __shared__ float s[4][2][8][66];   // [ch][pair-half][bin][col(+pad)]

    const float* __restrict__ xp = x + (((size_t)b * CC + c) << 12);

    // per-landmark params (k unrolled -> scalars, rule #20 safe)
    int fxA[2], roiA[2]; float binA[2]; bool visA[2];
    #pragma unroll
    for (int k = 0; k < 2; ++k) {
        int lmi = 2 * p + k;
        float x0 = lm[b * 16 + 2 * lmi];
        float y0 = lm[b * 16 + 2 * lmi + 1];
        visA[k] = (x0 > 0.0f) || (y0 > 0.0f);
        // torchvision column-swap semantics:
        // rois=(b,x1,x2,y1,y2) consumed as (b,start_w,start_h,end_w,end_h)
        int fx = (int)floorf(x0 * 0.25f);
        int fy = (int)floorf(y0 * 0.25f);
        fxA[k]  = fx;
        roiA[k] = max(fy - fx + 1, 1);        // roi_w == roi_h
        binA[k] = (float)roiA[k] * 0.125f;    // exact /8
    }
    bool slow0 = visA[0] && roiA[0] > 1;
    bool slow1 = visA[1] && roiA[1] > 1;

    // ---- stage 1: one streaming pass over window rows per slow landmark ----
    // Bins overlap by <=1 row (ceil/floor boundaries); vprev seeds the overlap.
    #pragma unroll
    for (int k = 0; k < 2; ++k) {
        bool slow = (k == 0) ? slow0 : slow1;
        if (!slow) continue;                   // wave-uniform
        int fx = fxA[k]; float bin = binA[k]; int roi = roiA[k];
        int h0 = min(max(fx, 0), HH);
        int h1 = min(max(fx + roi, 0), HH);

        int t = 0;
        int he_t = min(max((int)ceilf(bin) + fx, 0), HH);
        float acc = -FLT_MAX, vprev = -FLT_MAX;

        for (int r4 = h0; r4 < h1; r4 += 4) {
            int rmax = h1 - 1;
            // 4 independent loads in flight; each window row loaded exactly once
            float v0 = xp[(min(r4 + 0, rmax) << 6) + lane];
            float v1 = xp[(min(r4 + 1, rmax) << 6) + lane];
            float v2 = xp[(min(r4 + 2, rmax) << 6) + lane];
            float v3 = xp[(min(r4 + 3, rmax) << 6) + lane];
            #pragma unroll
            for (int kk = 0; kk < 4; ++kk) {
                int r = r4 + kk;
                if (r < h1) {
                    float v = (kk == 0) ? v0 : (kk == 1) ? v1 : (kk == 2) ? v2 : v3;
                    while (r >= he_t && t < 7) {     // flush finished bin(s)
                        s[wave][k][t][lane] = acc;
                        ++t;
                        int hs_n = min(max((int)floorf((float)t * bin) + fx, 0), HH);
                        he_t     = min(max((int)ceilf((float)(t + 1) * bin) + fx, 0), HH);
                        acc = (hs_n < r) ? vprev : -FLT_MAX;   // 1-row bin overlap
                    }
                    acc = fmaxf(acc, v);
                    vprev = v;
                }
            }
        }
        // tail flushes (virtual r = h1): remaining bins hold at most row h1-1
        s[wave][k][t][lane] = acc;
        while (t < 7) {
            ++t;
            int hs_n = min(max((int)floorf((float)t * bin) + fx, 0), HH);
            s[wave][k][t][lane] = (hs_n < h1) ? vprev : -FLT_MAX;
        }
    }
    if (slow0 || slow1) __syncthreads();       // block-uniform condition

    // ---- stage 2: lane=(i, jj): jj<8 -> lmi 2p cell (i,jj); jj>=8 -> 2p+1 ----
    // Wave's 64 stores per pass = 4 full 64B out-lines; 2 passes cover 8 rows.
    #pragma unroll
    for (int ii = 0; ii < 2; ++ii) {
        int i  = (lane >> 4) + 4 * ii;   // 0..7
        int jj = lane & 15;              // 0..15
        int k  = jj >> 3;
        int j  = jj & 7;
        int fx = fxA[k]; float bin = binA[k]; int roi = roiA[k]; bool vis = visA[k];

        int hs = min(max((int)floorf((float)i * bin) + fx, 0), HH);
        int he = min(max((int)ceilf((float)(i + 1) * bin) + fx, 0), HH);
        int ws = min(max((int)floorf((float)j * bin) + fx - 7, 0), WW);
        int we = min(max((int)ceilf((float)(j + 1) * bin) + fx - 7, 0), WW);
        bool empty = (he <= hs) || (we <= ws) || !vis;

        float m;
        if (empty) {
            m = 0.0f;
        } else if (roi == 1) {           // all 64 cells = single pixel (fx, fx-7)
            m = xp[(hs << 6) + ws];
        } else {
            m = -FLT_MAX;
            for (int w = ws; w < we; ++w)
                m = fmaxf(m, s[wave][k][i][w]);
        }
        int orow = 8 * p + i;            // 8*(lmi>>1)+i, same for both halves
        out[(((size_t)b * CC + c) * 32 + orow) * 16 + jj] = m;   // ocol == jj
    }
}

extern "C" void kernel_launch(void* const* d_in, const int* in_sizes, int n_in,
                              void* d_out, int out_size, void* d_ws, size_t ws_size,
                              hipStream_t stream) {
    const float* x  = (const float*)d_in[0];
    const float* lm = (const float*)d_in[1];
    float* out = (float*)d_out;

    int blocks = BB * 4 * 32;   // 4096
    roipool_kernel<<<blocks, 256, 0, stream>>>(x, lm, out);
}

// Round 9
// 29.403 us; speedup vs baseline: 1.2470x; 1.2470x over previous
//
#include <hip/hip_runtime.h>
#include <float.h>

#define BB 32
#define CC 128
#define HH 64
#define WW 64
#define CHB 16   // channels per block; wave = 1 channel (R4 structure, 16 waves/WG)

// Block = 1024 threads = 16 waves = 16 consecutive channels of one (b, lmi).
// Grid = 32*8*8 = 2048 blocks — same 32768 waves & per-wave work as R4,
// 4x fewer workgroups (tests WG-dispatch-rate hypothesis).
__global__ __launch_bounds__(1024) void roipool_kernel(
    const float* __restrict__ x,   // [B,C,64,64]
    const float* __restrict__ lm,  // [B,16]
    float* __restrict__ out)       // [B,C,32,16]
{
    int blk = blockIdx.x;
    int cg  = blk & 7;           // channel group (16 channels)
    int lmi = (blk >> 3) & 7;    // landmark
    int b   = blk >> 6;          // batch

    int tid  = threadIdx.x;
    int wave = tid >> 6;
    int lane = tid & 63;

    __shared__ float s[CHB][8][65];   // padded

    float x0 = lm[b * 16 + 2 * lmi];
    float y0 = lm[b * 16 + 2 * lmi + 1];
    bool visible = (x0 > 0.0f) || (y0 > 0.0f);

    // torchvision column-swap semantics:
    // rois=(b,x1,x2,y1,y2) consumed as (b,start_w,start_h,end_w,end_h)
    int fx = (int)floorf(x0 * 0.25f);
    int fy = (int)floorf(y0 * 0.25f);
    int roi = max(fy - fx + 1, 1);      // roi_w == roi_h
    float bin = (float)roi * 0.125f;    // exact /8

    int cbase = cg * CHB;

    // this thread's output cell (fast path / stage 2)
    int i = lane >> 3;
    int j = lane & 7;
    int orow = 8 * (lmi >> 1) + i;
    int ocol = 8 * (lmi & 1) + j;

    // ---------- fast path: roi==1 -> every cell is pixel (fx, fx-7) ----------
    if (roi == 1) {                     // block-uniform branch
        int hs = min(max(fx, 0), HH),     he = min(max(fx + 1, 0), HH);
        int ws = min(max(fx - 7, 0), WW), we = min(max(fx - 6, 0), WW);
        bool empty = (he <= hs) || (we <= ws) || !visible;
        size_t c = (size_t)(cbase + wave);
        float v = 0.0f;
        if (!empty) v = x[(((size_t)b * CC + c) << 12) + (hs << 6) + ws];
        out[(((size_t)b * CC + c) * 32 + orow) * 16 + ocol] = empty ? 0.0f : v;
        return;
    }

    // ---------- stage 1: per-column max per row-bin; wave = 1 channel ----------
    const float* __restrict__ xp =
        x + (((size_t)b * CC + (cbase + wave)) << 12) + lane;

    if (visible) {
        #pragma unroll
        for (int t = 0; t < 8; ++t) {
            int hs = min(max((int)floorf((float)t * bin) + fx, 0), HH);
            int he = min(max((int)ceilf((float)(t + 1) * bin) + fx, 0), HH);
            float acc = -FLT_MAX;
            for (int h = hs; h < he; h += 4) {
                // clamped duplicate rows harmless under max; 4 loads in flight
                int h1 = min(h + 1, he - 1);
                int h2 = min(h + 2, he - 1);
                int h3 = min(h + 3, he - 1);
                float v0 = xp[h  << 6];
                float v1 = xp[h1 << 6];
                float v2 = xp[h2 << 6];
                float v3 = xp[h3 << 6];
                acc = fmaxf(acc, fmaxf(fmaxf(v0, v1), fmaxf(v2, v3)));
            }
            s[wave][t][lane] = acc;
        }
    }
    __syncthreads();

    // ---------- stage 2: pool columns from LDS; thread = (channel, cell) ----------
    int hs = min(max((int)floorf((float)i * bin) + fx, 0), HH);
    int he = min(max((int)ceilf((float)(i + 1) * bin) + fx, 0), HH);
    int ws = min(max((int)floorf((float)j * bin) + fx - 7, 0), WW);
    int we = min(max((int)ceilf((float)(j + 1) * bin) + fx - 7, 0), WW);
    bool empty = (he <= hs) || (we <= ws) || !visible;

    float m = -FLT_MAX;
    if (!empty) {
        for (int w = ws; w < we; ++w)
            m = fmaxf(m, s[wave][i][w]);
    }
    out[(((size_t)b * CC + cbase + wave) * 32 + orow) * 16 + ocol] = empty ? 0.0f : m;
}

extern "C" void kernel_launch(void* const* d_in, const int* in_sizes, int n_in,
                              void* d_out, int out_size, void* d_ws, size_t ws_size,
                              hipStream_t stream) {
    const float* x  = (const float*)d_in[0];
    const float* lm = (const float*)d_in[1];
    float* out = (float*)d_out;

    int blocks = BB * 8 * (CC / CHB);   // 2048
    roipool_kernel<<<blocks, 1024, 0, stream>>>(x, lm, out);
}